// Round 4
// baseline (106.014 us; speedup 1.0000x reference)
//
#include <hip/hip_runtime.h>
#include <hip/hip_cooperative_groups.h>

namespace cg = cooperative_groups;

#define DEPTH 8
#define NINT 255          // internal nodes
#define NLEAF 256
#define BATCH 2048
#define NCLS 200
#define EPS 1e-7f
#define TB 8              // batch rows per block -> 256 blocks = 1/CU (= NLEAF)
#define LPAD 264          // padded leaf-dim row length in bf16 elems (528 B, 16B-aligned)
#define NTILE 13          // ceil(200/16) class tiles

typedef float f32x4 __attribute__((ext_vector_type(4)));
typedef __bf16 bf16x8 __attribute__((ext_vector_type(8)));
typedef unsigned short u16x8 __attribute__((ext_vector_type(8)));

// fast bf16 pack: round-half-up (add 0x8000, shift). Max rel err 2^-9 = 0.2%,
// -> <=0.004 abs error after the final log; threshold is 0.13.
static __device__ __forceinline__ unsigned short f2bf(float f) {
    unsigned int u = __builtin_bit_cast(unsigned int, f);
    return (unsigned short)((u + 0x8000u) >> 16);
}

// ---------------------------------------------------------------------------
// Fused cooperative kernel. 256 blocks; block l:
//   pre-sync : Et column l = bf16(exp(logit[l][:]) / Z_l)   (global d_ws)
//              + sims prefetch, phase a (pr/pl), phase b (W^T) — Et-independent
//   grid.sync()  — Et produced chip-wide; device-scope release/acquire
//   post-sync: MFMA 16x16x32, B read directly from Et (L3-hot), epilogue.
// Replaces the 2-kernel pipeline: softmax production now hides under the
// tree phases instead of serializing ahead of them (one fewer dispatch+gap).
// ---------------------------------------------------------------------------
__global__ __launch_bounds__(256) void tree_fused(
    const float* __restrict__ sims, const float* __restrict__ logits,
    unsigned short* __restrict__ Et, float* __restrict__ out) {
    __shared__ unsigned short Wt[16 * LPAD];           // W^T[b][l], bf16
    __shared__ float pr_s[NINT * TB];
    __shared__ float pl_s[NINT * TB];
    __shared__ float D_s[TB * NCLS];                   // 8x200 f32 exp-domain stage
    __shared__ float Zp[4];                            // per-wave Z partials

    const int tid = threadIdx.x;
    const int l = blockIdx.x;           // leaf owned for softmax production
    const int b0 = blockIdx.x * TB;     // batch octet for the GEMM

    // --- issue global loads early: logits row (800B coalesced) + sims ---
    const float lg = (tid < NCLS) ? logits[l * NCLS + tid] : 0.f;
    float prv[8];
#pragma unroll
    for (int p = 0; p < 8; ++p) {
        const int idx = tid + 256 * p;
        if (idx < NINT * TB)
            prv[p] = sims[(idx >> 3) * BATCH + b0 + (idx & 7)];
    }

    const int lane = tid & 63;
    const int wave = tid >> 6;

    // --- leaf softmax, part 1: exp + wave-level Z reduce ---
    const float ecl = (tid < NCLS) ? __expf(lg) : 0.f;
    {
        float z = ecl;
#pragma unroll
        for (int off = 32; off >= 1; off >>= 1)
            z += __shfl_xor(z, off);
        if (lane == 0) Zp[wave] = z;
    }

    // --- zero the pad rows MFMA will read (W rows 8..15) ---
    {
        unsigned int* wz = (unsigned int*)(Wt + 8 * LPAD);
        for (int i = tid; i < (8 * LPAD) / 2; i += 256) wz[i] = 0u;
    }

    // --- phase a: pr / p_left -> LDS, all-hardware transcendentals.
    // pl = log(1 - exp(pr-EPS)): worst pr=-0.01 -> arg ~0.00995, expf rel err
    // ~1ulp -> log abs err ~6e-6. ---
#pragma unroll
    for (int p = 0; p < 8; ++p) {
        const int idx = tid + 256 * p;
        if (idx < NINT * TB) {
            const float pr = prv[p];
            pr_s[idx] = pr;
            pl_s[idx] = __logf(1.0f - __expf(pr - EPS));
        }
    }
    __syncthreads();   // covers Zp + pr_s/pl_s

    // --- leaf softmax, part 2: Et[c][l] column write (rows 200..207 = pad 0) ---
    {
        const float Z = (Zp[0] + Zp[1]) + (Zp[2] + Zp[3]);
        const float invZ = __builtin_amdgcn_rcpf(Z);   // Z in [200e-3,200e3]: safe
        if (tid < NCLS)           Et[tid * NLEAF + l] = f2bf(ecl * invZ);
        else if (tid < NCLS + 8)  Et[tid * NLEAF + l] = 0;
    }

    // --- phase b: W^T[b][l] = exp(path) (bf16), rows 0..7.
    // Thread = (leaf-octet q, batch b): its 8 leaves form a depth-3 subtree.
    // Shared 5-edge prefix + tree expansion = 19 LDS reads (vs 64 for
    // independent walks) and ONE ds_write_b128 (vs 8 ds_write_b16). ---
    {
        const int q = tid >> 3;             // leaf octet 0..31
        const int b = tid & 7;
        const int a = 31 + q;               // depth-5 ancestor of leaves 8q..8q+7

        float s5 = 0.f;                     // root -> a prefix
        int n = a;
#pragma unroll
        for (int d = 0; d < 5; ++d) {
            const int par = (n - 1) >> 1;
            s5 += ((n & 1) == 0) ? pr_s[par * TB + b] : pl_s[par * TB + b];
            n = par;
        }
        // depth 6: children 2a+1 (left), 2a+2 (right)
        const float c60 = s5 + pl_s[a * TB + b];
        const float c61 = s5 + pr_s[a * TB + b];
        const int n60 = 2 * a + 1, n61 = 2 * a + 2;
        // depth 7
        const float c7[4] = { c60 + pl_s[n60 * TB + b], c60 + pr_s[n60 * TB + b],
                              c61 + pl_s[n61 * TB + b], c61 + pr_s[n61 * TB + b] };
        // depth 8 = leaves 255 + 8q + i; parent p7 = 127 + 4q + (i>>1)
        u16x8 wrow;
#pragma unroll
        for (int i = 0; i < 8; ++i) {
            const int j7 = i >> 1;
            const int p7 = 127 + 4 * q + j7;
            const float w = c7[j7] + ((i & 1) ? pr_s[p7 * TB + b]
                                              : pl_s[p7 * TB + b]);
            wrow[i] = f2bf(__expf(w));
        }
        *(u16x8*)(Wt + b * LPAD + 8 * q) = wrow;   // byte off = 528b+16q, 16B-aligned
    }

    // --- grid-wide barrier: Et complete & visible (device-scope rel/acq).
    // Also subsumes the block barrier protecting Wt. ---
    cg::this_grid().sync();

    // --- phase c: MFMA 16x16x32 bf16, K=256 (8 steps), 13 class tiles / 4 waves
    const int mn = lane & 15;               // A row (batch m) == B/D col (class n)
    const int quad = lane >> 4;
    const int t0 = wave, t1 = wave + 4, t2 = wave + 8, t3 = wave + 12;

    f32x4 acc0 = {0.f, 0.f, 0.f, 0.f};
    f32x4 acc1 = {0.f, 0.f, 0.f, 0.f};
    f32x4 acc2 = {0.f, 0.f, 0.f, 0.f};
    f32x4 acc3 = {0.f, 0.f, 0.f, 0.f};

#pragma unroll
    for (int s = 0; s < 8; ++s) {
        const int ko = s * 32 + quad * 8;   // k offset (elems); A/B k = quad*8+j
        const bf16x8 a = *(const bf16x8*)(Wt + mn * LPAD + ko);
        const bf16x8 bv0 = *(const bf16x8*)(Et + (t0 * 16 + mn) * NLEAF + ko);
        acc0 = __builtin_amdgcn_mfma_f32_16x16x32_bf16(a, bv0, acc0, 0, 0, 0);
        const bf16x8 bv1 = *(const bf16x8*)(Et + (t1 * 16 + mn) * NLEAF + ko);
        acc1 = __builtin_amdgcn_mfma_f32_16x16x32_bf16(a, bv1, acc1, 0, 0, 0);
        const bf16x8 bv2 = *(const bf16x8*)(Et + (t2 * 16 + mn) * NLEAF + ko);
        acc2 = __builtin_amdgcn_mfma_f32_16x16x32_bf16(a, bv2, acc2, 0, 0, 0);
        if (wave == 0) {                    // tile 12 (classes 192..207)
            const bf16x8 bv3 = *(const bf16x8*)(Et + (t3 * 16 + mn) * NLEAF + ko);
            acc3 = __builtin_amdgcn_mfma_f32_16x16x32_bf16(a, bv3, acc3, 0, 0, 0);
        }
    }

    // --- epilogue: stage exp-domain D in LDS, then coalesced log+store.
    // D col = lane&15, row = quad*4 + reg; valid rows 0..7. Block's output is
    // one contiguous 6400B span (rows b0..b0+7 complete). ---
    if (quad < 2) {
#pragma unroll
        for (int i = 0; i < 4; ++i) {
            const int t = (i == 0) ? t0 : (i == 1) ? t1 : (i == 2) ? t2 : t3;
            if (t >= NTILE) continue;
            const f32x4 acc = (i == 0) ? acc0 : (i == 1) ? acc1
                            : (i == 2) ? acc2 : acc3;
            const int c = t * 16 + mn;
            if (c < NCLS) {
#pragma unroll
                for (int r = 0; r < 4; ++r)
                    D_s[(quad * 4 + r) * NCLS + c] = acc[r];
            }
        }
    }
    __syncthreads();
    {
        f32x4* po = (f32x4*)(out + (size_t)b0 * NCLS);   // 6400B, 16B-aligned
        const f32x4* ps = (const f32x4*)D_s;
#pragma unroll
        for (int it = 0; it < 2; ++it) {
            const int idx = tid + 256 * it;
            if (idx < (TB * NCLS) / 4) {                 // 400 float4
                f32x4 v = ps[idx];
                v[0] = __logf(v[0]); v[1] = __logf(v[1]);
                v[2] = __logf(v[2]); v[3] = __logf(v[3]);
                po[idx] = v;
            }
        }
    }
}

extern "C" void kernel_launch(void* const* d_in, const int* in_sizes, int n_in,
                              void* d_out, int out_size, void* d_ws, size_t ws_size,
                              hipStream_t stream) {
    const float* sims = (const float*)d_in[0];       // [255, 2048] fp32
    const float* logits = (const float*)d_in[1];     // [256, 200]  fp32
    float* out = (float*)d_out;                      // [2048, 200] fp32
    unsigned short* Et = (unsigned short*)d_ws;      // [208, 256] bf16 (106.5 KB)

    void* args[] = { (void*)&sims, (void*)&logits, (void*)&Et, (void*)&out };
    // 256 blocks x 256 thr, 30.5 KB LDS -> 5 blocks/CU capacity >= 1 needed:
    // full grid co-resident, cooperative launch valid.
    hipLaunchCooperativeKernel((const void*)tree_fused, dim3(BATCH / TB),
                               dim3(256), args, 0, stream);
}

// Round 5
// 65.493 us; speedup vs baseline: 1.6187x; 1.6187x over previous
//
#include <hip/hip_runtime.h>

#define DEPTH 8
#define NINT 255          // internal nodes
#define NLEAF 256
#define BATCH 2048
#define NCLS 200
#define EPS 1e-7f
#define TB 8              // batch rows per block -> 256 blocks = 1/CU
#define LPAD 264          // padded leaf-dim row length in bf16 elems (528 B, 16B-aligned)
#define NTILE 13          // ceil(200/16) class tiles

typedef float f32x4 __attribute__((ext_vector_type(4)));
typedef __bf16 bf16x8 __attribute__((ext_vector_type(8)));
typedef unsigned short u16x8 __attribute__((ext_vector_type(8)));

// fast bf16 pack: round-half-up (add 0x8000, shift). Max rel err 2^-9 = 0.2%,
// -> <=0.004 abs error after the final log; threshold is 0.13.
static __device__ __forceinline__ unsigned short f2bf(float f) {
    unsigned int u = __builtin_bit_cast(unsigned int, f);
    return (unsigned short)((u + 0x8000u) >> 16);
}

// ---------------------------------------------------------------------------
// Kernel 1: E^T[c][l] = bf16( exp(logit[l][c]) / Z_l ), computed ONCE.
// Layout [208][256] bf16 in d_ws; rows 200..207 zeroed (MFMA tile-12 pad).
// One wave per leaf: coalesced 800B row load, shfl-reduce for Z.
// NOTE (R4 post-mortem): fusing this into tree_gemm via
// hipLaunchCooperativeKernel + grid.sync cost +40us — cooperative dispatch
// takes a runtime slow path on this harness. Two regular launches win.
// ---------------------------------------------------------------------------
__global__ __launch_bounds__(64) void leaf_softmax(
    const float* __restrict__ logits, unsigned short* __restrict__ Et) {
    const int l = blockIdx.x;          // leaf
    const int lane = threadIdx.x;      // 0..63
    const float* row = logits + l * NCLS;

    float e[4];
    float Z = 0.f;
#pragma unroll
    for (int j = 0; j < 4; ++j) {
        const int c = lane + 64 * j;
        e[j] = (c < NCLS) ? __expf(row[c]) : 0.f;
        Z += e[j];
    }
#pragma unroll
    for (int off = 32; off >= 1; off >>= 1)
        Z += __shfl_xor(Z, off);
    const float invZ = __builtin_amdgcn_rcpf(Z);   // Z in [200e-3,200e3]: safe

#pragma unroll
    for (int j = 0; j < 4; ++j) {
        const int c = lane + 64 * j;
        if (c < NCLS) Et[c * NLEAF + l] = f2bf(e[j] * invZ);
    }
    if (lane < 8) Et[(NCLS + lane) * NLEAF + l] = 0;  // pad rows 200..207
}

// ---------------------------------------------------------------------------
// Kernel 2: out[b,c] = log( sum_l exp(path(l,b)) * E[l,c] )
//   A (MFMA) = W^T[b][l] = exp(path)          (16 x 256, rows 8..15 zero, LDS)
//   B (MFMA) = E^T[c][l]                      (global, L3-hot from kernel 1)
// ---------------------------------------------------------------------------
__global__ __launch_bounds__(256) void tree_gemm(
    const float* __restrict__ sims, const unsigned short* __restrict__ Et,
    float* __restrict__ out) {
    __shared__ unsigned short Wt[16 * LPAD];           // W^T[b][l], bf16
    __shared__ float pr_s[NINT * TB];
    __shared__ float pl_s[NINT * TB];
    __shared__ float D_s[TB * NCLS];                   // 8x200 f32 exp-domain stage

    const int tid = threadIdx.x;
    const int b0 = blockIdx.x * TB;

    // --- issue sims loads early (HBM-cold) ---
    float prv[8];
#pragma unroll
    for (int p = 0; p < 8; ++p) {
        const int idx = tid + 256 * p;
        if (idx < NINT * TB)
            prv[p] = sims[(idx >> 3) * BATCH + b0 + (idx & 7)];
    }

    // --- MFMA lane mapping (needed for the B-fragment prefetch below) ---
    const int lane = tid & 63;
    const int wave = tid >> 6;
    const int mn = lane & 15;               // A row (batch m) == B/D col (class n)
    const int quad = lane >> 4;
    const int t0 = wave, t1 = wave + 4, t2 = wave + 8, t3 = wave + 12;

    // --- prefetch step-0 B fragments (L3-warm from kernel 1) ---
    const bf16x8 pb0 = *(const bf16x8*)(Et + (t0 * 16 + mn) * NLEAF + quad * 8);
    const bf16x8 pb1 = *(const bf16x8*)(Et + (t1 * 16 + mn) * NLEAF + quad * 8);
    const bf16x8 pb2 = *(const bf16x8*)(Et + (t2 * 16 + mn) * NLEAF + quad * 8);
    const bf16x8 pb3 = *(const bf16x8*)(Et + (t3 * 16 + mn) * NLEAF * (t3 < NTILE) + quad * 8);

    // --- zero the pad rows MFMA will read (W rows 8..15) ---
    {
        unsigned int* wz = (unsigned int*)(Wt + 8 * LPAD);
        for (int i = tid; i < (8 * LPAD) / 2; i += 256) wz[i] = 0u;
    }

    // --- phase a: pr / p_left -> LDS, all-hardware transcendentals.
    // pl = log(1 - exp(pr-EPS)): worst pr=-0.01 -> arg ~0.00995, expf rel err
    // ~1ulp -> log abs err ~6e-6. ---
#pragma unroll
    for (int p = 0; p < 8; ++p) {
        const int idx = tid + 256 * p;
        if (idx < NINT * TB) {
            const float pr = prv[p];
            pr_s[idx] = pr;
            pl_s[idx] = __logf(1.0f - __expf(pr - EPS));
        }
    }
    __syncthreads();

    // --- phase b: W^T[b][l] = exp(path) (bf16), rows 0..7.
    // Thread = (leaf-octet q, batch b): its 8 leaves form a depth-3 subtree.
    // Shared 5-edge prefix + tree expansion = 19 LDS reads (vs 64 for
    // independent walks) and ONE ds_write_b128 (vs 8 ds_write_b16). ---
    {
        const int q = tid >> 3;             // leaf octet 0..31
        const int b = tid & 7;
        const int a = 31 + q;               // depth-5 ancestor of leaves 8q..8q+7

        float s5 = 0.f;                     // root -> a prefix
        int n = a;
#pragma unroll
        for (int d = 0; d < 5; ++d) {
            const int par = (n - 1) >> 1;
            s5 += ((n & 1) == 0) ? pr_s[par * TB + b] : pl_s[par * TB + b];
            n = par;
        }
        // depth 6: children 2a+1 (left), 2a+2 (right)
        const float c60 = s5 + pl_s[a * TB + b];
        const float c61 = s5 + pr_s[a * TB + b];
        const int n60 = 2 * a + 1, n61 = 2 * a + 2;
        // depth 7
        const float c7[4] = { c60 + pl_s[n60 * TB + b], c60 + pr_s[n60 * TB + b],
                              c61 + pl_s[n61 * TB + b], c61 + pr_s[n61 * TB + b] };
        // depth 8 = leaves 255 + 8q + i; parent p7 = 127 + 4q + (i>>1)
        u16x8 wrow;
#pragma unroll
        for (int i = 0; i < 8; ++i) {
            const int j7 = i >> 1;
            const int p7 = 127 + 4 * q + j7;
            const float w = c7[j7] + ((i & 1) ? pr_s[p7 * TB + b]
                                              : pl_s[p7 * TB + b]);
            wrow[i] = f2bf(__expf(w));
        }
        *(u16x8*)(Wt + b * LPAD + 8 * q) = wrow;   // byte off = 528b+16q, 16B-aligned
    }
    __syncthreads();

    // --- phase c: MFMA 16x16x32 bf16, K=256 (8 steps), 13 class tiles / 4 waves
    f32x4 acc0 = {0.f, 0.f, 0.f, 0.f};
    f32x4 acc1 = {0.f, 0.f, 0.f, 0.f};
    f32x4 acc2 = {0.f, 0.f, 0.f, 0.f};
    f32x4 acc3 = {0.f, 0.f, 0.f, 0.f};

#pragma unroll
    for (int s = 0; s < 8; ++s) {
        const int ko = s * 32 + quad * 8;   // k offset (elems); A/B k = quad*8+j
        const bf16x8 a = *(const bf16x8*)(Wt + mn * LPAD + ko);
        const bf16x8 bv0 = (s == 0) ? pb0
                         : *(const bf16x8*)(Et + (t0 * 16 + mn) * NLEAF + ko);
        acc0 = __builtin_amdgcn_mfma_f32_16x16x32_bf16(a, bv0, acc0, 0, 0, 0);
        const bf16x8 bv1 = (s == 0) ? pb1
                         : *(const bf16x8*)(Et + (t1 * 16 + mn) * NLEAF + ko);
        acc1 = __builtin_amdgcn_mfma_f32_16x16x32_bf16(a, bv1, acc1, 0, 0, 0);
        const bf16x8 bv2 = (s == 0) ? pb2
                         : *(const bf16x8*)(Et + (t2 * 16 + mn) * NLEAF + ko);
        acc2 = __builtin_amdgcn_mfma_f32_16x16x32_bf16(a, bv2, acc2, 0, 0, 0);
        if (wave == 0) {                    // tile 12 (classes 192..207)
            const bf16x8 bv3 = (s == 0) ? pb3
                             : *(const bf16x8*)(Et + (t3 * 16 + mn) * NLEAF + ko);
            acc3 = __builtin_amdgcn_mfma_f32_16x16x32_bf16(a, bv3, acc3, 0, 0, 0);
        }
    }

    // --- epilogue: stage exp-domain D in LDS, then coalesced log+store.
    // D col = lane&15, row = quad*4 + reg; valid rows 0..7. Block's output is
    // one contiguous 6400B span (rows b0..b0+7 complete). ---
    if (quad < 2) {
#pragma unroll
        for (int i = 0; i < 4; ++i) {
            const int t = (i == 0) ? t0 : (i == 1) ? t1 : (i == 2) ? t2 : t3;
            if (t >= NTILE) continue;
            const f32x4 acc = (i == 0) ? acc0 : (i == 1) ? acc1
                            : (i == 2) ? acc2 : acc3;
            const int c = t * 16 + mn;
            if (c < NCLS) {
#pragma unroll
                for (int r = 0; r < 4; ++r)
                    D_s[(quad * 4 + r) * NCLS + c] = acc[r];
            }
        }
    }
    __syncthreads();
    {
        f32x4* po = (f32x4*)(out + (size_t)b0 * NCLS);   // 6400B, 16B-aligned
        const f32x4* ps = (const f32x4*)D_s;
#pragma unroll
        for (int it = 0; it < 2; ++it) {
            const int idx = tid + 256 * it;
            if (idx < (TB * NCLS) / 4) {                 // 400 float4
                f32x4 v = ps[idx];
                v[0] = __logf(v[0]); v[1] = __logf(v[1]);
                v[2] = __logf(v[2]); v[3] = __logf(v[3]);
                po[idx] = v;
            }
        }
    }
}

extern "C" void kernel_launch(void* const* d_in, const int* in_sizes, int n_in,
                              void* d_out, int out_size, void* d_ws, size_t ws_size,
                              hipStream_t stream) {
    const float* sims = (const float*)d_in[0];     // [255, 2048] fp32
    const float* logits = (const float*)d_in[1];   // [256, 200]  fp32
    float* out = (float*)d_out;                    // [2048, 200] fp32
    unsigned short* Et = (unsigned short*)d_ws;    // [208, 256] bf16 (106.5 KB)

    leaf_softmax<<<NLEAF, 64, 0, stream>>>(logits, Et);
    tree_gemm<<<BATCH / TB, 256, 0, stream>>>(sims, Et, out);
}